// Round 4
// baseline (396.575 us; speedup 1.0000x reference)
//
#include <hip/hip_runtime.h>
#include <stdint.h>

// Forward warp (scatter bilinear splat) as an ATOMIC-FREE output gather.
// img: (N=4, C=3, H=1080, W=1920) fp32
// flo: (N, 2, H, W) fp32; plane0=y (COLUMN offset), plane1=x (ROW offset).
// Scatter: out[n,c, h+floor(x)+dx, w+floor(y)+dy] += img[n,c,h,w] * wx*wy.
// Gather identity: source s=(h,w) contributes img[s]*tent(x_s-a)*tent(y_s-b)
// to out(h+a, w+b), tent(t)=max(0,1-|t|). Kernel 1 gathers all taps with
// |a|<=4 && |b|<=4 from an LDS-staged window into REGISTERS (no atomics,
// no memset, each output written once). Kernel 2 fixes up rare |flow|>4
// escapees (P~1e-4) with global atomics, per-tap exclusion -> exact.
//
// Round-1 lesson: LDS atomics lane-serialize (~2.3 cyc/lane) -> no atomics.
// Round-2 lesson: full 12x9 unroll => VGPR 256 + scratch spill @ 11% occ.
// Round-3 result: looped rows + launch_bounds(256,4): 218us, VALUBusy 90%
//   -> now VALU-ISSUE-bound. This round: cut instruction count via
//   (a) packed-f32 (v_pk_*) math: channel-pair FMAs + paired k tents
//       (tent as max(min(1-t,1+t),0) -- no abs, VOP3P-friendly),
//   (b) compile-time k-ranges per row (no mask muls, no dead taps);
//   prologue/epilogue rows are 6 separate inlined calls (uoff folds to a
//   literal), middle 6 rows remain a #pragma unroll 1 loop for pressure.

#define N_ 4
#define C_ 3
#define H_ 1080
#define W_ 1920
#define HW_ (H_ * W_)

#define TW 32
#define TH 32
#define HALO 4
#define WW (TW + 2 * HALO)  // 40
#define WH (TH + 2 * HALO)  // 40
#define NQ (WW / 4)         // 10 float4 quads per window row
#define PLANE_Q (WH * NQ)   // 400 quads per plane

typedef float v2f __attribute__((ext_vector_type(2)));

__device__ __forceinline__ v2f v2max(v2f a, v2f b) {
  return __builtin_elementwise_max(a, b);
}
__device__ __forceinline__ v2f v2min(v2f a, v2f b) {
  return __builtin_elementwise_min(a, b);
}

// Gather one source row into the per-thread 4-row accumulator strip.
// Valid output rows: k in [KMIN, KMAX] (= [max(0,dr-8), min(3,dr)]).
// acc01[k] = {c0,c1} accumulator (packed), acc2[k] = c2 accumulator.
template <int KMIN, int KMAX>
__device__ __forceinline__ void gather_row(const int wr, const float uoff,
                                           const int c,
                                           const float (*spack)[WW][4],
                                           const float (*sy)[WW],
                                           v2f acc01[4], float acc2[4]) {
#pragma unroll
  for (int dc = 0; dc < 9; ++dc) {
    const int wc = c + dc;
    const float4 f = *reinterpret_cast<const float4*>(&spack[wr][wc][0]);
    const float yv = sy[wr][wc];
    // column tent: b = HALO - dc (fabs folds into VOP3 abs modifier)
    const float ty = fmaxf(0.f, 1.f - fabsf(yv - (float)(HALO - dc)));
    const float u = f.w + uoff;  // x - a_k = u - k
    // pre-scale channels by ty once per visit
    const v2f c01t = (v2f){f.x, f.y} * ty;
    const float c2t = f.z * ty;
#pragma unroll
    for (int k0 = KMIN; k0 <= KMAX; k0 += 2) {
      if (k0 + 1 <= KMAX) {
        // packed pair {k0, k0+1}: tent(t) = max(min(1-t, 1+t), 0)
        const v2f t = u - (v2f){(float)k0, (float)(k0 + 1)};
        const v2f tx = v2max(v2min(1.f - t, 1.f + t), (v2f){0.f, 0.f});
        acc01[k0] += c01t * tx.x;
        acc2[k0] += c2t * tx.x;
        acc01[k0 + 1] += c01t * tx.y;
        acc2[k0 + 1] += c2t * tx.y;
      } else {
        const float t = u - (float)k0;
        const float tx = fmaxf(0.f, 1.f - fabsf(t));
        acc01[k0] += c01t * tx;
        acc2[k0] += c2t * tx;
      }
    }
  }
}

__global__ __launch_bounds__(256, 4) void fw_gather_kernel(
    const float* __restrict__ img, const float* __restrict__ flo,
    float* __restrict__ out) {
  __shared__ float spack[WH][WW][4];  // {c0,c1,c2,x}  25.6 KB
  __shared__ float sy[WH][WW];        // {y}            6.4 KB

  const int tid = threadIdx.x;
  const int C0 = blockIdx.x * TW;
  const int R0 = blockIdx.y * TH;
  const int n = blockIdx.z;
  const int base = n * C_ * HW_;
  const int fbase = n * 2 * HW_;

  // ---- stage 5 planes (y, x, c0, c1, c2) via float4 loads, zero-fill OOB.
  // Window cols are 4-aligned and W_%4==0 -> quad validity all-or-nothing.
  for (int id = tid; id < 5 * PLANE_Q; id += 256) {
    const int p = id / PLANE_Q;
    const int r = id - p * PLANE_Q;
    const int wr = r / NQ;
    const int q = r - wr * NQ;
    const int h = R0 - HALO + wr;
    const int w0 = C0 - HALO + 4 * q;
    float4 v = make_float4(0.f, 0.f, 0.f, 0.f);
    if ((unsigned)h < H_ && (unsigned)w0 < W_) {
      const float* src = (p == 0)   ? (flo + fbase)        // y plane
                         : (p == 1) ? (flo + fbase + HW_)  // x plane
                                    : (img + base + (p - 2) * HW_);
      v = *reinterpret_cast<const float4*>(src + h * W_ + w0);
    }
    const int wc = 4 * q;
    if (p == 0) {
      sy[wr][wc + 0] = v.x;
      sy[wr][wc + 1] = v.y;
      sy[wr][wc + 2] = v.z;
      sy[wr][wc + 3] = v.w;
    } else {
      const int ch = (p == 1) ? 3 : (p - 2);
      spack[wr][wc + 0][ch] = v.x;
      spack[wr][wc + 1][ch] = v.y;
      spack[wr][wc + 2][ch] = v.z;
      spack[wr][wc + 3][ch] = v.w;
    }
  }
  __syncthreads();

  // ---- register gather: thread owns a 4-row x 1-col output strip
  const int c = tid & (TW - 1);   // output col (tile-local)
  const int r0 = (tid >> 5) * 4;  // first output row of strip

  v2f acc01[4];
  float acc2[4];
#pragma unroll
  for (int k = 0; k < 4; ++k) {
    acc01[k] = (v2f){0.f, 0.f};
    acc2[k] = 0.f;
  }

  // Source rows wr = r0 + dr, dr in [0,12). Valid k: [max(0,dr-8), min(3,dr)].
  // Prologue/epilogue: compile-time dr (uoff literal), restricted k-range.
  gather_row<0, 0>(r0 + 0, -4.f, c, spack, sy, acc01, acc2);
  gather_row<0, 1>(r0 + 1, -3.f, c, spack, sy, acc01, acc2);
  gather_row<0, 2>(r0 + 2, -2.f, c, spack, sy, acc01, acc2);
#pragma unroll 1
  for (int dr = 3; dr < 9; ++dr)
    gather_row<0, 3>(r0 + dr, (float)(dr - HALO), c, spack, sy, acc01, acc2);
  gather_row<1, 3>(r0 + 9, 5.f, c, spack, sy, acc01, acc2);
  gather_row<2, 3>(r0 + 10, 6.f, c, spack, sy, acc01, acc2);
  gather_row<3, 3>(r0 + 11, 7.f, c, spack, sy, acc01, acc2);

  // ---- store: each output cell owned by exactly one thread
#pragma unroll
  for (int k = 0; k < 4; ++k) {
    const int h = R0 + r0 + k;
    if (h < H_) {
      const int o = base + h * W_ + C0 + c;
      out[o] = acc01[k].x;
      out[o + HW_] = acc01[k].y;
      out[o + 2 * HW_] = acc2[k];
    }
  }
}

// Fixup: taps with target offset outside [-HALO, HALO]^2 (not covered by the
// gather). float4-vectorized fast reject; rare slow path uses global atomics.
__global__ __launch_bounds__(256) void fw_fixup_kernel(
    const float* __restrict__ img, const float* __restrict__ flo,
    float* __restrict__ out) {
  const int t = blockIdx.x * blockDim.x + threadIdx.x;
  if (t >= (N_ * HW_) / 4) return;
  const int idx4 = t * 4;
  const int n = idx4 / HW_;
  const int hw4 = idx4 - n * HW_;  // HW_ % 4 == 0 -> all 4 px in same image

  const float4 yv =
      *reinterpret_cast<const float4*>(flo + (size_t)(n * 2 + 0) * HW_ + hw4);
  const float4 xv =
      *reinterpret_cast<const float4*>(flo + (size_t)(n * 2 + 1) * HW_ + hw4);

  const float ys[4] = {yv.x, yv.y, yv.z, yv.w};
  const float xs[4] = {xv.x, xv.y, xv.z, xv.w};

  // fast reject: x,y in [-HALO, HALO) => all 4 taps have |a|<=HALO, |b|<=HALO
  bool any = false;
#pragma unroll
  for (int k = 0; k < 4; ++k) {
    const bool inside = (xs[k] >= -(float)HALO) && (xs[k] < (float)HALO) &&
                        (ys[k] >= -(float)HALO) && (ys[k] < (float)HALO);
    any |= !inside;
  }
  if (!any) return;

  const int base = n * C_ * HW_;
#pragma unroll 1
  for (int k = 0; k < 4; ++k) {
    const float x = xs[k];
    const float y = ys[k];
    const bool inside = (x >= -(float)HALO) && (x < (float)HALO) &&
                        (y >= -(float)HALO) && (y < (float)HALO);
    if (inside) continue;

    const int hw = hw4 + k;
    const int h = hw / W_;
    const int w = hw - h * W_;
    const float x1 = floorf(x);
    const float y1 = floorf(y);
    const int ix = (int)x1;
    const int iy = (int)y1;
    const float fx = x - x1;
    const float fy = y - y1;
    const float c0 = img[base + 0 * HW_ + hw];
    const float c1 = img[base + 1 * HW_ + hw];
    const float c2 = img[base + 2 * HW_ + hw];

#pragma unroll
    for (int dx = 0; dx < 2; ++dx) {
      const int dh = h + ix + dx;
      if ((unsigned)dh >= H_) continue;
      const float wxw = dx ? fx : (1.0f - fx);
#pragma unroll
      for (int dy = 0; dy < 2; ++dy) {
        const int dw = w + iy + dy;
        if ((unsigned)dw >= W_) continue;
        const int a = ix + dx;  // target row offset
        const int b = iy + dy;  // target col offset
        if (a >= -HALO && a <= HALO && b >= -HALO && b <= HALO)
          continue;  // covered by gather kernel
        const float wt = wxw * (dy ? fy : (1.0f - fy));
        const int o = base + dh * W_ + dw;
        atomicAdd(out + o, c0 * wt);
        atomicAdd(out + o + HW_, c1 * wt);
        atomicAdd(out + o + 2 * HW_, c2 * wt);
      }
    }
  }
}

extern "C" void kernel_launch(void* const* d_in, const int* in_sizes, int n_in,
                              void* d_out, int out_size, void* d_ws,
                              size_t ws_size, hipStream_t stream) {
  const float* img = (const float*)d_in[0];
  const float* flo = (const float*)d_in[1];
  float* out = (float*)d_out;

  // No memset: fw_gather_kernel writes every output element exactly once.
  dim3 grid1(W_ / TW, (H_ + TH - 1) / TH, N_);  // 60 x 34 x 4
  fw_gather_kernel<<<grid1, 256, 0, stream>>>(img, flo, out);

  const int total4 = (N_ * HW_) / 4;
  fw_fixup_kernel<<<(total4 + 255) / 256, 256, 0, stream>>>(img, flo, out);
}